// Round 1
// baseline (394.086 us; speedup 1.0000x reference)
//
#include <hip/hip_runtime.h>
#include <cstdint>
#include <cstddef>

// Problem constants (from reference)
#define XL      432
#define YL      496
#define PLANE   (XL * YL)      // 214272 (y-major: idx = y*XL + x)
#define BSZ     4
#define NPIL    80000
#define NPTS    32
#define OUTC    64

static_assert(PLANE % 256 == 0, "scatter kernel assumes exact 256-thread tiling");

__device__ __forceinline__ float bf2f(uint16_t u) { return __uint_as_float(((uint32_t)u) << 16); }
__device__ __forceinline__ uint16_t f2bf(float f) {
    uint32_t x = __float_as_uint(f);
    x += 0x7fffu + ((x >> 16) & 1u);   // RTNE
    return (uint16_t)(x >> 16);
}
__device__ __forceinline__ float ld(const void* p, int i, bool bf) {
    return bf ? bf2f(((const uint16_t*)p)[i]) : ((const float*)p)[i];
}

// In-wave dtype probe on the first 64 words of `pillars` (wave-uniform data,
// L2-broadcast). bf16 data: low-half-as-bf16 is a real N(0,1) sample
// (plausible ~64/64). f32 data: low half is mantissa bits -> uniform exponent
// (plausible ~20/64, sigma 3.7). Threshold 40 is >5 sigma from both.
__device__ __forceinline__ bool probe_bf16(const void* pillars) {
    const int lane = threadIdx.x & 63;
    uint32_t w = ((const uint32_t*)pillars)[lane];
    float a = fabsf(__uint_as_float(w << 16));
    bool pl = (a > 1e-20f) && (a < 1e4f);
    return __popcll(__ballot(pl)) >= 40;
}

// Kernel 1: one wave per pillar, lane = output channel. BN folded into conv
// weights; the 9 affine features collapse to a 4-FMA dot + per-pillar const.
// Point loop unrolled x2 with dual max accumulators (breaks fmax serial chain).
__global__ __launch_bounds__(256) void pillar_feat_kernel(
    const void* __restrict__ pillars,   // (P, 32, 4) bf16 or f32
    const int*  __restrict__ npoints,   // (P,)
    const int*  __restrict__ coors,     // (P, 4): b, x, y, 0
    const void* __restrict__ conv_w,    // (64, 9)
    const void* __restrict__ gamma,
    const void* __restrict__ beta,
    const void* __restrict__ mean,
    const void* __restrict__ var,
    float*      __restrict__ pooled,    // f32 (P, 64)
    int*        __restrict__ map)       // (BSZ, PLANE), pre-filled -1
{
    const bool bf  = probe_bf16(pillars);
    const int lane = threadIdx.x & 63;
    const int wave = threadIdx.x >> 6;
    const int p    = blockIdx.x * 4 + wave;   // 20000 blocks * 4 waves = 80000

    // per-channel constants: fold BN into conv weights
    const float scale  = ld(gamma, lane, bf) * __frsqrt_rn(ld(var, lane, bf) + 1e-3f);
    const float bprime = ld(beta, lane, bf) - ld(mean, lane, bf) * scale;

    float w[9];
    #pragma unroll
    for (int k = 0; k < 9; ++k) w[k] = ld(conv_w, lane * 9 + k, bf) * scale;

    // features affine in raw point (x,y,z,i): 9-dot -> 4-dot + pillar constant
    const float ax = w[0] + w[4] + w[7];
    const float ay = w[1] + w[5] + w[8];
    const float az = w[2] + w[6];
    const float ai = w[3];

    const int np = npoints[p];
    const int cb = coors[p * 4 + 0];
    const int cx = coors[p * 4 + 1];
    const int cy = coors[p * 4 + 2];

    const size_t base = (size_t)p * NPTS;

    // unmasked sum of x,y,z over all 32 points; lanes 0-31 / 32-63 mirror-load,
    // xor-butterfly 1..16 leaves the full sum in every lane.
    float sx, sy, sz;
    if (bf) {
        uint2 d = ((const uint2*)pillars)[base + (lane & 31)];
        sx = __uint_as_float(d.x << 16);
        sy = __uint_as_float(d.x & 0xffff0000u);
        sz = __uint_as_float(d.y << 16);
    } else {
        float4 d = ((const float4*)pillars)[base + (lane & 31)];
        sx = d.x; sy = d.y; sz = d.z;
    }
    #pragma unroll
    for (int m = 1; m <= 16; m <<= 1) {
        sx += __shfl_xor(sx, m, 64);
        sy += __shfl_xor(sy, m, 64);
        sz += __shfl_xor(sz, m, 64);
    }
    const float inv = 1.0f / (float)np;
    const float gx = (float)cx * 0.16f + 0.08f;
    const float gy = (float)cy * 0.16f + (0.08f - 39.68f);
    const float Kc = bprime - inv * (sx * w[4] + sy * w[5] + sz * w[6])
                            - gx * w[7] - gy * w[8];

    // masked rows contribute b' pre-relu; relu(max) == max(relu)
    float m0 = (np < NPTS) ? bprime : -3.0e38f;
    float m1 = -3.0e38f;
    int n = 0;
    if (bf) {
        const uint2* pp = (const uint2*)pillars + base;
        for (; n + 2 <= np; n += 2) {
            uint2 qa = pp[n];
            uint2 qb = pp[n + 1];
            float va = Kc, vb = Kc;
            va = fmaf(__uint_as_float(qa.x << 16),         ax, va);
            va = fmaf(__uint_as_float(qa.x & 0xffff0000u), ay, va);
            va = fmaf(__uint_as_float(qa.y << 16),         az, va);
            va = fmaf(__uint_as_float(qa.y & 0xffff0000u), ai, va);
            vb = fmaf(__uint_as_float(qb.x << 16),         ax, vb);
            vb = fmaf(__uint_as_float(qb.x & 0xffff0000u), ay, vb);
            vb = fmaf(__uint_as_float(qb.y << 16),         az, vb);
            vb = fmaf(__uint_as_float(qb.y & 0xffff0000u), ai, vb);
            m0 = fmaxf(m0, va);
            m1 = fmaxf(m1, vb);
        }
        if (n < np) {
            uint2 qa = pp[n];
            float va = Kc;
            va = fmaf(__uint_as_float(qa.x << 16),         ax, va);
            va = fmaf(__uint_as_float(qa.x & 0xffff0000u), ay, va);
            va = fmaf(__uint_as_float(qa.y << 16),         az, va);
            va = fmaf(__uint_as_float(qa.y & 0xffff0000u), ai, va);
            m0 = fmaxf(m0, va);
        }
    } else {
        const float4* pp = (const float4*)pillars + base;
        for (; n + 2 <= np; n += 2) {
            float4 qa = pp[n];
            float4 qb = pp[n + 1];
            float va = Kc, vb = Kc;
            va = fmaf(qa.x, ax, va); va = fmaf(qa.y, ay, va);
            va = fmaf(qa.z, az, va); va = fmaf(qa.w, ai, va);
            vb = fmaf(qb.x, ax, vb); vb = fmaf(qb.y, ay, vb);
            vb = fmaf(qb.z, az, vb); vb = fmaf(qb.w, ai, vb);
            m0 = fmaxf(m0, va);
            m1 = fmaxf(m1, vb);
        }
        if (n < np) {
            float4 qa = pp[n];
            float va = Kc;
            va = fmaf(qa.x, ax, va); va = fmaf(qa.y, ay, va);
            va = fmaf(qa.z, az, va); va = fmaf(qa.w, ai, va);
            m0 = fmaxf(m0, va);
        }
    }
    float m = fmaxf(fmaxf(m0, m1), 0.0f);

    pooled[(size_t)p * OUTC + lane] = m;   // 64 lanes x 4B = 256B coalesced
    if (lane == 0) map[cb * PLANE + cy * XL + cx] = p;
}

// Kernel 2: one thread per canvas cell, all 64 channels.
//  - map read exactly once (4B/lane, coalesced): 3.4 MB instead of 8x27 MB
//  - pooled row streamed as 16x float4: every fetched 64B line fully used
//    (the 4 float4s of a line hit L1 across consecutive cg iterations)
//  - canvas stores nontemporal: 219 MB stream bypasses L2, keeps map/pooled
//    lines resident. Per channel a wave writes 64x4B = 256B contiguous.
__global__ __launch_bounds__(256) void scatter_canvas_kernel(
    const void*  __restrict__ pillars,   // only for dtype probe
    const int*   __restrict__ map,
    const float* __restrict__ pooled,
    void*        __restrict__ out)
{
    const bool bf = probe_bf16(pillars);
    const int b  = blockIdx.y;
    const int e  = blockIdx.x * 256 + threadIdx.x;   // PLANE == 837*256, no tail

    const int idx = map[b * PLANE + e];
    const bool occ = idx >= 0;
    // clamp to row 0 when empty: keeps the address valid; empty lanes all hit
    // the same L1-resident line if the compiler speculates the load.
    const float4* __restrict__ row =
        (const float4*)(pooled + (size_t)(occ ? idx : 0) * OUTC);

    if (bf) {
        uint16_t* o = (uint16_t*)out + (size_t)b * OUTC * PLANE + e;
        #pragma unroll
        for (int cg = 0; cg < 16; ++cg) {
            float4 r = occ ? row[cg] : make_float4(0.f, 0.f, 0.f, 0.f);
            __builtin_nontemporal_store(f2bf(r.x), o + (size_t)(cg * 4 + 0) * PLANE);
            __builtin_nontemporal_store(f2bf(r.y), o + (size_t)(cg * 4 + 1) * PLANE);
            __builtin_nontemporal_store(f2bf(r.z), o + (size_t)(cg * 4 + 2) * PLANE);
            __builtin_nontemporal_store(f2bf(r.w), o + (size_t)(cg * 4 + 3) * PLANE);
        }
    } else {
        float* o = (float*)out + (size_t)b * OUTC * PLANE + e;
        #pragma unroll
        for (int cg = 0; cg < 16; ++cg) {
            float4 r = occ ? row[cg] : make_float4(0.f, 0.f, 0.f, 0.f);
            __builtin_nontemporal_store(r.x, o + (size_t)(cg * 4 + 0) * PLANE);
            __builtin_nontemporal_store(r.y, o + (size_t)(cg * 4 + 1) * PLANE);
            __builtin_nontemporal_store(r.z, o + (size_t)(cg * 4 + 2) * PLANE);
            __builtin_nontemporal_store(r.w, o + (size_t)(cg * 4 + 3) * PLANE);
        }
    }
}

extern "C" void kernel_launch(void* const* d_in, const int* in_sizes, int n_in,
                              void* d_out, int out_size, void* d_ws, size_t ws_size,
                              hipStream_t stream) {
    (void)in_sizes; (void)n_in; (void)out_size; (void)ws_size;

    // ws layout: [map: BSZ*PLANE int = 3.27 MB][pooled: NPIL*64 f32 = 20.5 MB]
    int*   map    = (int*)d_ws;
    float* pooled = (float*)((char*)d_ws + sizeof(int) * (size_t)BSZ * PLANE);

    hipMemsetAsync(map, 0xFF, sizeof(int) * (size_t)BSZ * PLANE, stream);

    pillar_feat_kernel<<<NPIL / 4, 256, 0, stream>>>(
        d_in[0], (const int*)d_in[1], (const int*)d_in[2],
        d_in[3], d_in[4], d_in[5], d_in[6], d_in[7],
        pooled, map);

    dim3 g2(PLANE / 256, BSZ);
    scatter_canvas_kernel<<<g2, 256, 0, stream>>>(d_in[0], map, pooled, d_out);
}

// Round 2
// 348.495 us; speedup vs baseline: 1.1308x; 1.1308x over previous
//
#include <hip/hip_runtime.h>
#include <cstdint>
#include <cstddef>

// Problem constants (from reference)
#define XL      432
#define YL      496
#define PLANE   (XL * YL)      // 214272 (y-major: idx = y*XL + x)
#define BSZ     4
#define NPIL    80000
#define NPTS    32
#define OUTC    64

__device__ __forceinline__ float bf2f(uint16_t u) { return __uint_as_float(((uint32_t)u) << 16); }
__device__ __forceinline__ uint16_t f2bf(float f) {
    uint32_t x = __float_as_uint(f);
    x += 0x7fffu + ((x >> 16) & 1u);   // RTNE
    return (uint16_t)(x >> 16);
}
__device__ __forceinline__ float ld(const void* p, int i, bool bf) {
    return bf ? bf2f(((const uint16_t*)p)[i]) : ((const float*)p)[i];
}

// In-wave dtype probe on the first 64 words of `pillars` (wave-uniform data,
// L2-broadcast). bf16 data: low-half-as-bf16 is a real N(0,1) sample
// (plausible ~64/64). f32 data: low half is mantissa bits -> uniform exponent
// (plausible ~20/64, sigma 3.7). Threshold 40 is >5 sigma from both.
__device__ __forceinline__ bool probe_bf16(const void* pillars) {
    const int lane = threadIdx.x & 63;
    uint32_t w = ((const uint32_t*)pillars)[lane];
    float a = fabsf(__uint_as_float(w << 16));
    bool pl = (a > 1e-20f) && (a < 1e4f);
    return __popcll(__ballot(pl)) >= 40;
}

// Kernel 1: one wave per pillar, lane = output channel. BN folded into conv
// weights; the 9 affine features collapse to a 4-FMA dot + per-pillar const.
// Point loop unrolled x2 with dual max accumulators (breaks fmax serial chain).
__global__ __launch_bounds__(256) void pillar_feat_kernel(
    const void* __restrict__ pillars,   // (P, 32, 4) bf16 or f32
    const int*  __restrict__ npoints,   // (P,)
    const int*  __restrict__ coors,     // (P, 4): b, x, y, 0
    const void* __restrict__ conv_w,    // (64, 9)
    const void* __restrict__ gamma,
    const void* __restrict__ beta,
    const void* __restrict__ mean,
    const void* __restrict__ var,
    float*      __restrict__ pooled,    // f32 (P, 64)
    int*        __restrict__ map)       // (BSZ, PLANE), pre-filled -1
{
    const bool bf  = probe_bf16(pillars);
    const int lane = threadIdx.x & 63;
    const int wave = threadIdx.x >> 6;
    const int p    = blockIdx.x * 4 + wave;   // 20000 blocks * 4 waves = 80000

    // per-channel constants: fold BN into conv weights
    const float scale  = ld(gamma, lane, bf) * __frsqrt_rn(ld(var, lane, bf) + 1e-3f);
    const float bprime = ld(beta, lane, bf) - ld(mean, lane, bf) * scale;

    float w[9];
    #pragma unroll
    for (int k = 0; k < 9; ++k) w[k] = ld(conv_w, lane * 9 + k, bf) * scale;

    // features affine in raw point (x,y,z,i): 9-dot -> 4-dot + pillar constant
    const float ax = w[0] + w[4] + w[7];
    const float ay = w[1] + w[5] + w[8];
    const float az = w[2] + w[6];
    const float ai = w[3];

    const int np = npoints[p];
    const int cb = coors[p * 4 + 0];
    const int cx = coors[p * 4 + 1];
    const int cy = coors[p * 4 + 2];

    const size_t base = (size_t)p * NPTS;

    // unmasked sum of x,y,z over all 32 points; lanes 0-31 / 32-63 mirror-load,
    // xor-butterfly 1..16 leaves the full sum in every lane.
    float sx, sy, sz;
    if (bf) {
        uint2 d = ((const uint2*)pillars)[base + (lane & 31)];
        sx = __uint_as_float(d.x << 16);
        sy = __uint_as_float(d.x & 0xffff0000u);
        sz = __uint_as_float(d.y << 16);
    } else {
        float4 d = ((const float4*)pillars)[base + (lane & 31)];
        sx = d.x; sy = d.y; sz = d.z;
    }
    #pragma unroll
    for (int m = 1; m <= 16; m <<= 1) {
        sx += __shfl_xor(sx, m, 64);
        sy += __shfl_xor(sy, m, 64);
        sz += __shfl_xor(sz, m, 64);
    }
    const float inv = 1.0f / (float)np;
    const float gx = (float)cx * 0.16f + 0.08f;
    const float gy = (float)cy * 0.16f + (0.08f - 39.68f);
    const float Kc = bprime - inv * (sx * w[4] + sy * w[5] + sz * w[6])
                            - gx * w[7] - gy * w[8];

    // masked rows contribute b' pre-relu; relu(max) == max(relu)
    float m0 = (np < NPTS) ? bprime : -3.0e38f;
    float m1 = -3.0e38f;
    int n = 0;
    if (bf) {
        const uint2* pp = (const uint2*)pillars + base;
        for (; n + 2 <= np; n += 2) {
            uint2 qa = pp[n];
            uint2 qb = pp[n + 1];
            float va = Kc, vb = Kc;
            va = fmaf(__uint_as_float(qa.x << 16),         ax, va);
            va = fmaf(__uint_as_float(qa.x & 0xffff0000u), ay, va);
            va = fmaf(__uint_as_float(qa.y << 16),         az, va);
            va = fmaf(__uint_as_float(qa.y & 0xffff0000u), ai, va);
            vb = fmaf(__uint_as_float(qb.x << 16),         ax, vb);
            vb = fmaf(__uint_as_float(qb.x & 0xffff0000u), ay, vb);
            vb = fmaf(__uint_as_float(qb.y << 16),         az, vb);
            vb = fmaf(__uint_as_float(qb.y & 0xffff0000u), ai, vb);
            m0 = fmaxf(m0, va);
            m1 = fmaxf(m1, vb);
        }
        if (n < np) {
            uint2 qa = pp[n];
            float va = Kc;
            va = fmaf(__uint_as_float(qa.x << 16),         ax, va);
            va = fmaf(__uint_as_float(qa.x & 0xffff0000u), ay, va);
            va = fmaf(__uint_as_float(qa.y << 16),         az, va);
            va = fmaf(__uint_as_float(qa.y & 0xffff0000u), ai, va);
            m0 = fmaxf(m0, va);
        }
    } else {
        const float4* pp = (const float4*)pillars + base;
        for (; n + 2 <= np; n += 2) {
            float4 qa = pp[n];
            float4 qb = pp[n + 1];
            float va = Kc, vb = Kc;
            va = fmaf(qa.x, ax, va); va = fmaf(qa.y, ay, va);
            va = fmaf(qa.z, az, va); va = fmaf(qa.w, ai, va);
            vb = fmaf(qb.x, ax, vb); vb = fmaf(qb.y, ay, vb);
            vb = fmaf(qb.z, az, vb); vb = fmaf(qb.w, ai, vb);
            m0 = fmaxf(m0, va);
            m1 = fmaxf(m1, vb);
        }
        if (n < np) {
            float4 qa = pp[n];
            float va = Kc;
            va = fmaf(qa.x, ax, va); va = fmaf(qa.y, ay, va);
            va = fmaf(qa.z, az, va); va = fmaf(qa.w, ai, va);
            m0 = fmaxf(m0, va);
        }
    }
    float m = fmaxf(fmaxf(m0, m1), 0.0f);

    pooled[(size_t)p * OUTC + lane] = m;   // 64 lanes x 4B = 256B coalesced
    if (lane == 0) map[cb * PLANE + cy * XL + cx] = p;
}

// Kernel 2: round-0 store shape (ushort4/float4 per channel, 512B-1KB per
// wave-instruction, regular L2 write-back — the nt 2B-store variant regressed
// 55us), with the read side tightened: blockIdx.y = (b, half) where half picks
// 32 channels. map is read 2x (6.8 MB) instead of 8x (27 MB); each occupied
// pooled row is read as two 128B contiguous chunks (no 64B-line over-fetch).
__global__ __launch_bounds__(256) void scatter_canvas_kernel(
    const void*  __restrict__ pillars,   // only for dtype probe
    const int*   __restrict__ map,
    const float* __restrict__ pooled,
    void*        __restrict__ out)
{
    const bool bf = probe_bf16(pillars);
    const int by   = blockIdx.y;         // b*2 + half
    const int b    = by >> 1;
    const int half = by & 1;             // channels half*32 .. half*32+31
    const int e    = (blockIdx.x * 256 + threadIdx.x) * 4;
    if (e >= PLANE) return;

    int4 m4 = *(const int4*)(map + b * PLANE + e);
    const int idx[4] = {m4.x, m4.y, m4.z, m4.w};

    #pragma unroll
    for (int cg = 0; cg < 4; ++cg) {
        const int c0 = half * 32 + cg * 8;
        float v[4][8];
        #pragma unroll
        for (int i = 0; i < 4; ++i) {
            if (idx[i] >= 0) {
                const float4* row = (const float4*)(pooled + (size_t)idx[i] * OUTC + c0);
                float4 lo = row[0], hi = row[1];
                v[i][0] = lo.x; v[i][1] = lo.y; v[i][2] = lo.z; v[i][3] = lo.w;
                v[i][4] = hi.x; v[i][5] = hi.y; v[i][6] = hi.z; v[i][7] = hi.w;
            } else {
                #pragma unroll
                for (int j = 0; j < 8; ++j) v[i][j] = 0.0f;
            }
        }
        if (bf) {
            uint16_t* o16 = (uint16_t*)out;
            #pragma unroll
            for (int j = 0; j < 8; ++j) {
                ushort4 s;
                s.x = f2bf(v[0][j]); s.y = f2bf(v[1][j]);
                s.z = f2bf(v[2][j]); s.w = f2bf(v[3][j]);
                *(ushort4*)(o16 + (size_t)(b * OUTC + c0 + j) * PLANE + e) = s;
            }
        } else {
            float* o32 = (float*)out;
            #pragma unroll
            for (int j = 0; j < 8; ++j) {
                *(float4*)(o32 + (size_t)(b * OUTC + c0 + j) * PLANE + e) =
                    make_float4(v[0][j], v[1][j], v[2][j], v[3][j]);
            }
        }
    }
}

extern "C" void kernel_launch(void* const* d_in, const int* in_sizes, int n_in,
                              void* d_out, int out_size, void* d_ws, size_t ws_size,
                              hipStream_t stream) {
    (void)in_sizes; (void)n_in; (void)out_size; (void)ws_size;

    // ws layout: [map: BSZ*PLANE int = 3.27 MB][pooled: NPIL*64 f32 = 20.5 MB]
    int*   map    = (int*)d_ws;
    float* pooled = (float*)((char*)d_ws + sizeof(int) * (size_t)BSZ * PLANE);

    hipMemsetAsync(map, 0xFF, sizeof(int) * (size_t)BSZ * PLANE, stream);

    pillar_feat_kernel<<<NPIL / 4, 256, 0, stream>>>(
        d_in[0], (const int*)d_in[1], (const int*)d_in[2],
        d_in[3], d_in[4], d_in[5], d_in[6], d_in[7],
        pooled, map);

    dim3 g2((PLANE / 4 + 255) / 256, BSZ * 2);
    scatter_canvas_kernel<<<g2, 256, 0, stream>>>(d_in[0], map, pooled, d_out);
}

// Round 3
// 347.726 us; speedup vs baseline: 1.1333x; 1.0022x over previous
//
#include <hip/hip_runtime.h>
#include <cstdint>
#include <cstddef>

// Problem constants (from reference)
#define XL      432
#define YL      496
#define PLANE   (XL * YL)      // 214272 (y-major: idx = y*XL + x)
#define BSZ     4
#define NPIL    80000
#define NPTS    32
#define OUTC    64

__device__ __forceinline__ float bf2f(uint16_t u) { return __uint_as_float(((uint32_t)u) << 16); }
__device__ __forceinline__ uint16_t f2bf(float f) {
    uint32_t x = __float_as_uint(f);
    x += 0x7fffu + ((x >> 16) & 1u);   // RTNE
    return (uint16_t)(x >> 16);
}
__device__ __forceinline__ float ld(const void* p, int i, bool bf) {
    return bf ? bf2f(((const uint16_t*)p)[i]) : ((const float*)p)[i];
}

// In-wave dtype probe on the first 64 words of `pillars` (wave-uniform data,
// L2-broadcast). bf16 data: low-half-as-bf16 is a real N(0,1) sample
// (plausible ~64/64). f32 data: low half is mantissa bits -> uniform exponent
// (plausible ~20/64, sigma 3.7). Threshold 40 is >5 sigma from both.
__device__ __forceinline__ bool probe_bf16(const void* pillars) {
    const int lane = threadIdx.x & 63;
    uint32_t w = ((const uint32_t*)pillars)[lane];
    float a = fabsf(__uint_as_float(w << 16));
    bool pl = (a > 1e-20f) && (a < 1e4f);
    return __popcll(__ballot(pl)) >= 40;
}

// Kernel 1: one wave per pillar, lane = output channel. BN folded into conv
// weights; the 9 affine features collapse to a 4-FMA dot + per-pillar const.
// Point loop unrolled x2 with dual max accumulators (breaks fmax serial chain).
// pooled is stored in OUTPUT dtype: bf16 when input is bf16 (single RTNE here,
// k2 then copies raw u16 -> final bits identical to converting in k2), f32 else.
__global__ __launch_bounds__(256) void pillar_feat_kernel(
    const void* __restrict__ pillars,   // (P, 32, 4) bf16 or f32
    const int*  __restrict__ npoints,   // (P,)
    const int*  __restrict__ coors,     // (P, 4): b, x, y, 0
    const void* __restrict__ conv_w,    // (64, 9)
    const void* __restrict__ gamma,
    const void* __restrict__ beta,
    const void* __restrict__ mean,
    const void* __restrict__ var,
    void*       __restrict__ pooled,    // (P, 64) bf16 or f32 (matches input dtype)
    int*        __restrict__ map)       // (BSZ, PLANE), pre-filled -1
{
    const bool bf  = probe_bf16(pillars);
    const int lane = threadIdx.x & 63;
    const int wave = threadIdx.x >> 6;
    const int p    = blockIdx.x * 4 + wave;   // 20000 blocks * 4 waves = 80000

    // per-channel constants: fold BN into conv weights
    const float scale  = ld(gamma, lane, bf) * __frsqrt_rn(ld(var, lane, bf) + 1e-3f);
    const float bprime = ld(beta, lane, bf) - ld(mean, lane, bf) * scale;

    float w[9];
    #pragma unroll
    for (int k = 0; k < 9; ++k) w[k] = ld(conv_w, lane * 9 + k, bf) * scale;

    // features affine in raw point (x,y,z,i): 9-dot -> 4-dot + pillar constant
    const float ax = w[0] + w[4] + w[7];
    const float ay = w[1] + w[5] + w[8];
    const float az = w[2] + w[6];
    const float ai = w[3];

    const int np = npoints[p];
    const int cb = coors[p * 4 + 0];
    const int cx = coors[p * 4 + 1];
    const int cy = coors[p * 4 + 2];

    const size_t base = (size_t)p * NPTS;

    // unmasked sum of x,y,z over all 32 points; lanes 0-31 / 32-63 mirror-load,
    // xor-butterfly 1..16 leaves the full sum in every lane.
    float sx, sy, sz;
    if (bf) {
        uint2 d = ((const uint2*)pillars)[base + (lane & 31)];
        sx = __uint_as_float(d.x << 16);
        sy = __uint_as_float(d.x & 0xffff0000u);
        sz = __uint_as_float(d.y << 16);
    } else {
        float4 d = ((const float4*)pillars)[base + (lane & 31)];
        sx = d.x; sy = d.y; sz = d.z;
    }
    #pragma unroll
    for (int m = 1; m <= 16; m <<= 1) {
        sx += __shfl_xor(sx, m, 64);
        sy += __shfl_xor(sy, m, 64);
        sz += __shfl_xor(sz, m, 64);
    }
    const float inv = 1.0f / (float)np;
    const float gx = (float)cx * 0.16f + 0.08f;
    const float gy = (float)cy * 0.16f + (0.08f - 39.68f);
    const float Kc = bprime - inv * (sx * w[4] + sy * w[5] + sz * w[6])
                            - gx * w[7] - gy * w[8];

    // masked rows contribute b' pre-relu; relu(max) == max(relu)
    float m0 = (np < NPTS) ? bprime : -3.0e38f;
    float m1 = -3.0e38f;
    int n = 0;
    if (bf) {
        const uint2* pp = (const uint2*)pillars + base;
        for (; n + 2 <= np; n += 2) {
            uint2 qa = pp[n];
            uint2 qb = pp[n + 1];
            float va = Kc, vb = Kc;
            va = fmaf(__uint_as_float(qa.x << 16),         ax, va);
            va = fmaf(__uint_as_float(qa.x & 0xffff0000u), ay, va);
            va = fmaf(__uint_as_float(qa.y << 16),         az, va);
            va = fmaf(__uint_as_float(qa.y & 0xffff0000u), ai, va);
            vb = fmaf(__uint_as_float(qb.x << 16),         ax, vb);
            vb = fmaf(__uint_as_float(qb.x & 0xffff0000u), ay, vb);
            vb = fmaf(__uint_as_float(qb.y << 16),         az, vb);
            vb = fmaf(__uint_as_float(qb.y & 0xffff0000u), ai, vb);
            m0 = fmaxf(m0, va);
            m1 = fmaxf(m1, vb);
        }
        if (n < np) {
            uint2 qa = pp[n];
            float va = Kc;
            va = fmaf(__uint_as_float(qa.x << 16),         ax, va);
            va = fmaf(__uint_as_float(qa.x & 0xffff0000u), ay, va);
            va = fmaf(__uint_as_float(qa.y << 16),         az, va);
            va = fmaf(__uint_as_float(qa.y & 0xffff0000u), ai, va);
            m0 = fmaxf(m0, va);
        }
    } else {
        const float4* pp = (const float4*)pillars + base;
        for (; n + 2 <= np; n += 2) {
            float4 qa = pp[n];
            float4 qb = pp[n + 1];
            float va = Kc, vb = Kc;
            va = fmaf(qa.x, ax, va); va = fmaf(qa.y, ay, va);
            va = fmaf(qa.z, az, va); va = fmaf(qa.w, ai, va);
            vb = fmaf(qb.x, ax, vb); vb = fmaf(qb.y, ay, vb);
            vb = fmaf(qb.z, az, vb); vb = fmaf(qb.w, ai, vb);
            m0 = fmaxf(m0, va);
            m1 = fmaxf(m1, vb);
        }
        if (n < np) {
            float4 qa = pp[n];
            float va = Kc;
            va = fmaf(qa.x, ax, va); va = fmaf(qa.y, ay, va);
            va = fmaf(qa.z, az, va); va = fmaf(qa.w, ai, va);
            m0 = fmaxf(m0, va);
        }
    }
    float m = fmaxf(fmaxf(m0, m1), 0.0f);

    if (bf) {
        ((uint16_t*)pooled)[(size_t)p * OUTC + lane] = f2bf(m);  // 128B coalesced
    } else {
        ((float*)pooled)[(size_t)p * OUTC + lane] = m;           // 256B coalesced
    }
    if (lane == 0) map[cb * PLANE + cy * XL + cx] = p;
}

// Kernel 2: proven r0/r2 store shape (ushort4/float4 per channel, 512B-1KB per
// wave-instruction, regular L2 write-back). blockIdx.y = (b, half), half = 32
// channels. bf16 path: pooled already holds u16 payloads, so a cell's 8-channel
// block is ONE uint4 load and each output dword is 2-3 bitops (no f2bf here).
__global__ __launch_bounds__(256) void scatter_canvas_kernel(
    const void*  __restrict__ pillars,   // only for dtype probe
    const int*   __restrict__ map,
    const void*  __restrict__ pooled,    // (P,64) bf16 or f32
    void*        __restrict__ out)
{
    const bool bf = probe_bf16(pillars);
    const int by   = blockIdx.y;         // b*2 + half
    const int b    = by >> 1;
    const int half = by & 1;             // channels half*32 .. half*32+31
    const int e    = (blockIdx.x * 256 + threadIdx.x) * 4;
    if (e >= PLANE) return;

    int4 m4 = *(const int4*)(map + b * PLANE + e);
    const int idx[4] = {m4.x, m4.y, m4.z, m4.w};

    if (bf) {
        const uint16_t* p16 = (const uint16_t*)pooled;
        uint16_t* o16 = (uint16_t*)out;
        #pragma unroll
        for (int cg = 0; cg < 4; ++cg) {
            const int c0 = half * 32 + cg * 8;
            // r[i]: 8 channels (4 dwords, lo16 = even ch) of cell i's pillar row
            uint4 r[4];
            #pragma unroll
            for (int i = 0; i < 4; ++i) {
                r[i] = (idx[i] >= 0)
                     ? *(const uint4*)(p16 + (size_t)idx[i] * OUTC + c0)
                     : make_uint4(0u, 0u, 0u, 0u);
            }
            const uint32_t dw[4][4] = {
                {r[0].x, r[0].y, r[0].z, r[0].w},
                {r[1].x, r[1].y, r[1].z, r[1].w},
                {r[2].x, r[2].y, r[2].z, r[2].w},
                {r[3].x, r[3].y, r[3].z, r[3].w}};
            #pragma unroll
            for (int jp = 0; jp < 4; ++jp) {   // channel pair c0+2jp, c0+2jp+1
                const uint32_t a = dw[0][jp], bb = dw[1][jp];
                const uint32_t c = dw[2][jp], dd = dw[3][jp];
                // even channel: lo16 of each cell's dword
                uint2 se;
                se.x = (a & 0xffffu) | (bb << 16);
                se.y = (c & 0xffffu) | (dd << 16);
                *(uint2*)(o16 + (size_t)(b * OUTC + c0 + 2 * jp) * PLANE + e) = se;
                // odd channel: hi16 of each cell's dword
                uint2 so;
                so.x = (a >> 16) | (bb & 0xffff0000u);
                so.y = (c >> 16) | (dd & 0xffff0000u);
                *(uint2*)(o16 + (size_t)(b * OUTC + c0 + 2 * jp + 1) * PLANE + e) = so;
            }
        }
    } else {
        const float* pf = (const float*)pooled;
        float* o32 = (float*)out;
        #pragma unroll
        for (int cg = 0; cg < 4; ++cg) {
            const int c0 = half * 32 + cg * 8;
            float v[4][8];
            #pragma unroll
            for (int i = 0; i < 4; ++i) {
                if (idx[i] >= 0) {
                    const float4* row = (const float4*)(pf + (size_t)idx[i] * OUTC + c0);
                    float4 lo = row[0], hi = row[1];
                    v[i][0] = lo.x; v[i][1] = lo.y; v[i][2] = lo.z; v[i][3] = lo.w;
                    v[i][4] = hi.x; v[i][5] = hi.y; v[i][6] = hi.z; v[i][7] = hi.w;
                } else {
                    #pragma unroll
                    for (int j = 0; j < 8; ++j) v[i][j] = 0.0f;
                }
            }
            #pragma unroll
            for (int j = 0; j < 8; ++j) {
                *(float4*)(o32 + (size_t)(b * OUTC + c0 + j) * PLANE + e) =
                    make_float4(v[0][j], v[1][j], v[2][j], v[3][j]);
            }
        }
    }
}

extern "C" void kernel_launch(void* const* d_in, const int* in_sizes, int n_in,
                              void* d_out, int out_size, void* d_ws, size_t ws_size,
                              hipStream_t stream) {
    (void)in_sizes; (void)n_in; (void)out_size; (void)ws_size;

    // ws layout: [map: BSZ*PLANE int = 3.27 MB][pooled: NPIL*64 (bf16 or f32)]
    // pooled offset 3,428,352 B is 16B-aligned (uint4 loads in k2).
    int*  map    = (int*)d_ws;
    void* pooled = (void*)((char*)d_ws + sizeof(int) * (size_t)BSZ * PLANE);

    hipMemsetAsync(map, 0xFF, sizeof(int) * (size_t)BSZ * PLANE, stream);

    pillar_feat_kernel<<<NPIL / 4, 256, 0, stream>>>(
        d_in[0], (const int*)d_in[1], (const int*)d_in[2],
        d_in[3], d_in[4], d_in[5], d_in[6], d_in[7],
        pooled, map);

    dim3 g2((PLANE / 4 + 255) / 256, BSZ * 2);
    scatter_canvas_kernel<<<g2, 256, 0, stream>>>(d_in[0], map, pooled, d_out);
}